// Round 1
// baseline (783.189 us; speedup 1.0000x reference)
//
#include <hip/hip_runtime.h>
#include <hip/hip_bf16.h>
#include <stdint.h>

// Problem constants (fixed by the reference file)
#define B_ 2
#define N_ 20000
#define H_ 256
#define E_ 160000
#define M_ 512
// K1 = 2H = 512, hidden = M = 512, K2 = M = 512, out = H = 256

typedef short bf16x8 __attribute__((ext_vector_type(8)));
typedef float f32x4 __attribute__((ext_vector_type(4)));

__device__ __forceinline__ unsigned short f2bf(float f) {
    union { float f; unsigned u; } cv; cv.f = f;
    unsigned u = cv.u;
    unsigned r = u + 0x7fffu + ((u >> 16) & 1u);  // round-to-nearest-even
    return (unsigned short)(r >> 16);
}

__device__ __forceinline__ unsigned pack2(float a, float b) {
    return (unsigned)f2bf(a) | ((unsigned)f2bf(b) << 16);
}

// Transpose + convert weights: Wt[n*K + k] = bf16(W[k*Ncol + n])
__global__ void conv_t(const float* __restrict__ W, unsigned short* __restrict__ Wt,
                       int K, int Ncol) {
    int kcCount = K >> 3;
    int total = Ncol * kcCount;
    for (int idx = blockIdx.x * blockDim.x + threadIdx.x; idx < total;
         idx += gridDim.x * blockDim.x) {
        int n  = idx % Ncol;
        int kc = (idx / Ncol) << 3;
        unsigned short t[8];
#pragma unroll
        for (int j = 0; j < 8; ++j) t[j] = f2bf(W[(size_t)(kc + j) * Ncol + n]);
        uint4 v;
        v.x = (unsigned)t[0] | ((unsigned)t[1] << 16);
        v.y = (unsigned)t[2] | ((unsigned)t[3] << 16);
        v.z = (unsigned)t[4] | ((unsigned)t[5] << 16);
        v.w = (unsigned)t[6] | ((unsigned)t[7] << 16);
        *(uint4*)(Wt + (size_t)n * K + kc) = v;
    }
}

// Fused 2-layer MLP over 64-row tiles.
// MODE 0: rows = b*E + e; X = [h[b,src[e]], h[b,dst[e]]]; out: atomicAdd into agg[b,dst[e],:]
// MODE 1: rows = b*N + n; X = [h[b,n], agg[b,n]];        out: out = h + (MLP out)
template <int MODE>
__global__ __launch_bounds__(256, 2) void mlp_kernel(
    const float* __restrict__ h,
    const int* __restrict__ eidx,      // [2][E] (MODE 0 only)
    const float* __restrict__ aggin,   // (MODE 1 only)
    const unsigned short* __restrict__ W1t,  // [512][512] bf16, [n][k]
    const float* __restrict__ b1,            // [512]
    const unsigned short* __restrict__ W2t,  // [256][512] bf16, [n][k]
    const float* __restrict__ b2,            // [256]
    float* __restrict__ outp) {
    __shared__ char smem[64 * 1024];   // X tile, then hidden tile (both [64][512] bf16, swizzled)
    __shared__ int s_ga[64], s_gb[64], s_sc[64];

    const int tid  = threadIdx.x;
    const int row0 = blockIdx.x * 64;

    if (tid < 64) {
        int grow = row0 + tid;
        if (MODE == 0) {
            int b = (grow >= E_) ? 1 : 0;
            int e = grow - b * E_;
            s_ga[tid] = b * N_ + eidx[e];
            int d = b * N_ + eidx[E_ + e];
            s_gb[tid] = d;
            s_sc[tid] = d;
        } else {
            s_ga[tid] = grow;  // b*N + n == grow
            s_gb[tid] = grow;
            s_sc[tid] = grow;
        }
    }
    __syncthreads();

    // ---- gather 64 rows x 512 fp32 -> bf16 LDS (XOR-swizzled rows) ----
#pragma unroll
    for (int it = 0; it < 32; ++it) {
        int linear = it * 256 + tid;   // 0..8191
        int row = linear >> 7;         // /128 float4s per row
        int c4  = linear & 127;
        const float* base;
        if (c4 < 64) {
            base = h + ((size_t)s_ga[row] * H_ + (size_t)c4 * 4);
        } else {
            const float* second = (MODE == 0) ? h : aggin;
            base = second + ((size_t)s_gb[row] * H_ + (size_t)(c4 - 64) * 4);
        }
        float4 v = *(const float4*)base;
        int byte = (row * 1024 + c4 * 8) ^ ((row & 7) << 4);
        uint2 p;
        p.x = pack2(v.x, v.y);
        p.y = pack2(v.z, v.w);
        *(uint2*)(smem + byte) = p;
    }
    __syncthreads();

    const int lane = tid & 63;
    const int w    = tid >> 6;   // wave 0..3
    const int lo   = lane & 15;
    const int hi   = lane >> 4;

    // ---- GEMM1: hidden = relu(X @ W1 + b1); wave w owns cols [128w,128w+128) ----
    f32x4 acc[4][8];
#pragma unroll
    for (int i = 0; i < 4; ++i)
#pragma unroll
        for (int j = 0; j < 8; ++j) acc[i][j] = (f32x4){0.f, 0.f, 0.f, 0.f};

    for (int ks = 0; ks < 512; ks += 32) {
        bf16x8 af[4];
#pragma unroll
        for (int rf = 0; rf < 4; ++rf) {
            int row  = rf * 16 + lo;
            int byte = (row * 1024 + (ks + 8 * hi) * 2) ^ ((row & 7) << 4);
            af[rf] = *(const bf16x8*)(smem + byte);
        }
#pragma unroll
        for (int cf = 0; cf < 8; ++cf) {
            int col = w * 128 + cf * 16 + lo;
            bf16x8 bfr = *(const bf16x8*)(W1t + (size_t)col * 512 + ks + 8 * hi);
#pragma unroll
            for (int rf = 0; rf < 4; ++rf)
                acc[rf][cf] = __builtin_amdgcn_mfma_f32_16x16x32_bf16(af[rf], bfr, acc[rf][cf], 0, 0, 0);
        }
    }

    __syncthreads();  // all waves done reading X tile

    // bias + relu + bf16 -> hidden tile (reuse smem)
#pragma unroll
    for (int cf = 0; cf < 8; ++cf) {
        int col  = w * 128 + cf * 16 + lo;
        float bb = b1[col];
#pragma unroll
        for (int rf = 0; rf < 4; ++rf) {
#pragma unroll
            for (int r = 0; r < 4; ++r) {
                float v = fmaxf(acc[rf][cf][r] + bb, 0.f);
                int row  = rf * 16 + hi * 4 + r;
                int byte = (row * 1024 + col * 2) ^ ((row & 7) << 4);
                *(unsigned short*)(smem + byte) = f2bf(v);
            }
        }
    }
    __syncthreads();

    // ---- GEMM2: y = hidden @ W2 + b2; wave w owns cols [64w, 64w+64) ----
    f32x4 acc2[4][4];
#pragma unroll
    for (int i = 0; i < 4; ++i)
#pragma unroll
        for (int j = 0; j < 4; ++j) acc2[i][j] = (f32x4){0.f, 0.f, 0.f, 0.f};

    for (int ks = 0; ks < 512; ks += 32) {
        bf16x8 af[4];
#pragma unroll
        for (int rf = 0; rf < 4; ++rf) {
            int row  = rf * 16 + lo;
            int byte = (row * 1024 + (ks + 8 * hi) * 2) ^ ((row & 7) << 4);
            af[rf] = *(const bf16x8*)(smem + byte);
        }
#pragma unroll
        for (int cf = 0; cf < 4; ++cf) {
            int col = w * 64 + cf * 16 + lo;
            bf16x8 bfr = *(const bf16x8*)(W2t + (size_t)col * 512 + ks + 8 * hi);
#pragma unroll
            for (int rf = 0; rf < 4; ++rf)
                acc2[rf][cf] = __builtin_amdgcn_mfma_f32_16x16x32_bf16(af[rf], bfr, acc2[rf][cf], 0, 0, 0);
        }
    }

    // ---- epilogue ----
#pragma unroll
    for (int cf = 0; cf < 4; ++cf) {
        int col  = w * 64 + cf * 16 + lo;
        float bb = b2[col];
#pragma unroll
        for (int rf = 0; rf < 4; ++rf) {
#pragma unroll
            for (int r = 0; r < 4; ++r) {
                int row = rf * 16 + hi * 4 + r;
                float v = acc2[rf][cf][r] + bb;
                if (MODE == 0) {
                    atomicAdd(outp + (size_t)s_sc[row] * H_ + col, v);
                } else {
                    size_t o = (size_t)s_ga[row] * H_ + col;
                    outp[o] = h[o] + v;
                }
            }
        }
    }
}

extern "C" void kernel_launch(void* const* d_in, const int* in_sizes, int n_in,
                              void* d_out, int out_size, void* d_ws, size_t ws_size,
                              hipStream_t stream) {
    const float* h      = (const float*)d_in[0];
    const int*   eidx   = (const int*)d_in[1];
    const float* msg_w1 = (const float*)d_in[2];
    const float* msg_b1 = (const float*)d_in[3];
    const float* msg_w2 = (const float*)d_in[4];
    const float* msg_b2 = (const float*)d_in[5];
    const float* upd_w1 = (const float*)d_in[6];
    const float* upd_b1 = (const float*)d_in[7];
    const float* upd_w2 = (const float*)d_in[8];
    const float* upd_b2 = (const float*)d_in[9];
    float* out = (float*)d_out;

    char* ws = (char*)d_ws;
    size_t aggBytes = (size_t)B_ * N_ * H_ * sizeof(float);  // 40.96 MB
    float* agg = (float*)ws;
    size_t off = (aggBytes + 255) & ~(size_t)255;
    unsigned short* w1t = (unsigned short*)(ws + off); off += 512 * 512 * 2;
    unsigned short* w2t = (unsigned short*)(ws + off); off += 256 * 512 * 2;
    unsigned short* u1t = (unsigned short*)(ws + off); off += 512 * 512 * 2;
    unsigned short* u2t = (unsigned short*)(ws + off); off += 256 * 512 * 2;
    if (ws_size < off) return;  // workspace too small: fail cleanly

    hipMemsetAsync(agg, 0, aggBytes, stream);
    conv_t<<<128, 256, 0, stream>>>(msg_w1, w1t, 512, 512);
    conv_t<<<128, 256, 0, stream>>>(msg_w2, w2t, 512, 256);
    conv_t<<<128, 256, 0, stream>>>(upd_w1, u1t, 512, 512);
    conv_t<<<128, 256, 0, stream>>>(upd_w2, u2t, 512, 256);

    mlp_kernel<0><<<(B_ * E_) / 64, 256, 0, stream>>>(h, eidx, nullptr, w1t, msg_b1, w2t, msg_b2, agg);
    mlp_kernel<1><<<(B_ * N_) / 64, 256, 0, stream>>>(h, nullptr, agg, u1t, upd_b1, u2t, upd_b2, out);
}

// Round 2
// 487.350 us; speedup vs baseline: 1.6070x; 1.6070x over previous
//
#include <hip/hip_runtime.h>
#include <hip/hip_bf16.h>
#include <stdint.h>

#define B_ 2
#define N_ 20000
#define H_ 256
#define E_ 160000
#define M_ 512

typedef short bf16x8 __attribute__((ext_vector_type(8)));
typedef float f32x4 __attribute__((ext_vector_type(4)));

__device__ __forceinline__ unsigned short f2bf(float f) {
    union { float f; unsigned u; } cv; cv.f = f;
    unsigned u = cv.u;
    unsigned r = u + 0x7fffu + ((u >> 16) & 1u);
    return (unsigned short)(r >> 16);
}
__device__ __forceinline__ unsigned pack2(float a, float b) {
    return (unsigned)f2bf(a) | ((unsigned)f2bf(b) << 16);
}
__device__ __forceinline__ float bflo(unsigned p) {
    union { unsigned u; float f; } c; c.u = p << 16; return c.f;
}
__device__ __forceinline__ float bfhi(unsigned p) {
    union { unsigned u; float f; } c; c.u = p & 0xffff0000u; return c.f;
}

// ---------- weight transpose: Wt[n*K + k] = bf16(W[k*Ncol + n]) ----------
__global__ void conv_t(const float* __restrict__ W, unsigned short* __restrict__ Wt,
                       int K, int Ncol) {
    int total = Ncol * (K >> 3);
    for (int idx = blockIdx.x * blockDim.x + threadIdx.x; idx < total;
         idx += gridDim.x * blockDim.x) {
        int n = idx % Ncol;
        int kc = (idx / Ncol) << 3;
        unsigned short t[8];
#pragma unroll
        for (int j = 0; j < 8; ++j) t[j] = f2bf(W[(size_t)(kc + j) * Ncol + n]);
        uint4 v;
        v.x = (unsigned)t[0] | ((unsigned)t[1] << 16);
        v.y = (unsigned)t[2] | ((unsigned)t[3] << 16);
        v.z = (unsigned)t[4] | ((unsigned)t[5] << 16);
        v.w = (unsigned)t[6] | ((unsigned)t[7] << 16);
        *(uint4*)(Wt + (size_t)n * K + kc) = v;
    }
}

// W1pq_t[jj][kk] (jj<1024, kk<256): jj<512 -> P col jj = W1[kk][jj]; jj>=512 -> Q col = W1[kk+256][jj-512]
__global__ void conv_w1pq(const float* __restrict__ W, unsigned short* __restrict__ Wt) {
    int total = 1024 * 32;
    for (int idx = blockIdx.x * blockDim.x + threadIdx.x; idx < total;
         idx += gridDim.x * blockDim.x) {
        int jj = idx & 1023;
        int kc = (idx >> 10) << 3;
        int koff = (jj >= 512) ? 256 : 0;
        int j = jj & 511;
        unsigned short t[8];
#pragma unroll
        for (int r = 0; r < 8; ++r) t[r] = f2bf(W[(size_t)(kc + r + koff) * 512 + j]);
        uint4 v;
        v.x = (unsigned)t[0] | ((unsigned)t[1] << 16);
        v.y = (unsigned)t[2] | ((unsigned)t[3] << 16);
        v.z = (unsigned)t[4] | ((unsigned)t[5] << 16);
        v.w = (unsigned)t[6] | ((unsigned)t[7] << 16);
        *(uint4*)(Wt + (size_t)jj * 256 + kc) = v;
    }
}

// ---------- edge sort by dst (counting sort) ----------
__global__ void hist_kernel(const int* __restrict__ eidx, int* __restrict__ cnt) {
    for (int e = blockIdx.x * blockDim.x + threadIdx.x; e < E_;
         e += gridDim.x * blockDim.x)
        atomicAdd(cnt + eidx[E_ + e], 1);
}

__global__ void scan_kernel(const int* __restrict__ cnt, int* __restrict__ offs,
                            int* __restrict__ cursor) {
    __shared__ int part[1024];
    int t = threadIdx.x;
    int base_i = t * 20;
    int loc[20];
    int s = 0;
#pragma unroll 20
    for (int i = 0; i < 20; ++i) {
        int idx = base_i + i;
        int v = (idx < N_) ? cnt[idx] : 0;
        loc[i] = s;
        s += v;
    }
    part[t] = s;
    __syncthreads();
    for (int off = 1; off < 1024; off <<= 1) {
        int tmp = (t >= off) ? part[t - off] : 0;
        __syncthreads();
        if (t >= off) part[t] += tmp;
        __syncthreads();
    }
    int base = part[t] - s;
#pragma unroll 20
    for (int i = 0; i < 20; ++i) {
        int idx = base_i + i;
        if (idx < N_) {
            int o = base + loc[i];
            offs[idx] = o;
            cursor[idx] = o;
        }
    }
    if (t == 1023) offs[N_] = part[1023];
}

__global__ void scatter_kernel(const int* __restrict__ eidx, int* __restrict__ cursor,
                               int* __restrict__ sorted) {
    for (int e = blockIdx.x * blockDim.x + threadIdx.x; e < E_;
         e += gridDim.x * blockDim.x) {
        int d = eidx[E_ + e];
        int pos = atomicAdd(cursor + d, 1);
        sorted[pos] = e;
    }
}

// ---------- PQ = h_b @ [W1a | W1b]  (rows 20000, K=256, cols 1024) ----------
// 32-row tiles, 512 threads (8 waves), wave w owns cols [128w, 128w+128)
__global__ __launch_bounds__(512, 4) void pq_gemm(
    const float* __restrict__ hb,             // h + b*N*H
    const unsigned short* __restrict__ W1pq,  // [1024][256] bf16
    unsigned short* __restrict__ PQ) {        // [20000][1024] bf16
    __shared__ char smem[32 * 512];  // 32 rows x 256 bf16 (512B/row), swizzled
    const int tid = threadIdx.x;
    const int row0 = blockIdx.x * 32;

    // gather: 32 rows x 64 float4 = 2048 chunks; 512 threads x 4 iters
#pragma unroll
    for (int it = 0; it < 4; ++it) {
        int linear = it * 512 + tid;
        int row = linear >> 6;
        int c4 = linear & 63;
        float4 v = *(const float4*)(hb + (size_t)(row0 + row) * H_ + c4 * 4);
        int byte = (row * 512 + c4 * 8) ^ ((row & 7) << 4);
        uint2 p;
        p.x = pack2(v.x, v.y);
        p.y = pack2(v.z, v.w);
        *(uint2*)(smem + byte) = p;
    }
    __syncthreads();

    const int lane = tid & 63;
    const int w = tid >> 6;
    const int lo = lane & 15;
    const int hi = lane >> 4;

    f32x4 acc[2][8];
#pragma unroll
    for (int i = 0; i < 2; ++i)
#pragma unroll
        for (int j = 0; j < 8; ++j) acc[i][j] = (f32x4){0.f, 0.f, 0.f, 0.f};

    for (int ks = 0; ks < 256; ks += 32) {
        bf16x8 af[2];
#pragma unroll
        for (int rf = 0; rf < 2; ++rf) {
            int row = rf * 16 + lo;
            int byte = (row * 512 + (ks + 8 * hi) * 2) ^ ((row & 7) << 4);
            af[rf] = *(const bf16x8*)(smem + byte);
        }
#pragma unroll
        for (int cf = 0; cf < 8; ++cf) {
            int col = w * 128 + cf * 16 + lo;
            bf16x8 bfr = *(const bf16x8*)(W1pq + (size_t)col * 256 + ks + 8 * hi);
#pragma unroll
            for (int rf = 0; rf < 2; ++rf)
                acc[rf][cf] = __builtin_amdgcn_mfma_f32_16x16x32_bf16(af[rf], bfr, acc[rf][cf], 0, 0, 0);
        }
    }

#pragma unroll
    for (int cf = 0; cf < 8; ++cf) {
        int col = w * 128 + cf * 16 + lo;
#pragma unroll
        for (int rf = 0; rf < 2; ++rf) {
#pragma unroll
            for (int r = 0; r < 4; ++r) {
                int row = rf * 16 + hi * 4 + r;
                PQ[(size_t)(row0 + row) * 1024 + col] = f2bf(acc[rf][cf][r]);
            }
        }
    }
}

// ---------- aggregate + GEMM2: agg[d] = (sum_e relu(P[src]+Q[d]+b1)) @ W2 + cnt[d]*b2 ----------
// block: 32 dsts, 512 threads. Phase A: 16 threads/dst x 32 cols each, f32 accum in regs.
__global__ __launch_bounds__(512, 4) void agg_kernel(
    const unsigned short* __restrict__ PQ,    // [20000][1024] bf16 for this batch
    const int* __restrict__ eidx,             // src = eidx[e]
    const int* __restrict__ sorted,           // [E]
    const int* __restrict__ offs,             // [N+1]
    const int* __restrict__ cnt,              // [N]
    const unsigned short* __restrict__ w2t,   // [256][512] bf16
    const float* __restrict__ b1,             // [512]
    const float* __restrict__ b2,             // [256]
    unsigned short* __restrict__ aggb) {      // [20000][256] bf16 for this batch
    __shared__ char smem[32 * 1024];  // 32 rows x 512 bf16, swizzled
    const int tid = threadIdx.x;
    const int d0 = blockIdx.x * 32;
    const int dsub = tid >> 4;
    const int part = tid & 15;
    const int c0 = part * 32;
    const int d = d0 + dsub;

    // qb = bf16(Q[d] + b1) packed, 16 regs
    unsigned qb[16];
    {
        const unsigned short* qrow = PQ + (size_t)d * 1024 + 512 + c0;
#pragma unroll
        for (int c = 0; c < 4; ++c) {
            bf16x8 qv = *(const bf16x8*)(qrow + c * 8);
#pragma unroll
            for (int jp = 0; jp < 4; ++jp) {
                float q0 = bflo((unsigned)(unsigned short)qv[jp * 2]) + b1[c0 + c * 8 + jp * 2];
                float q1 = bflo((unsigned)(unsigned short)qv[jp * 2 + 1]) + b1[c0 + c * 8 + jp * 2 + 1];
                qb[c * 4 + jp] = pack2(q0, q1);
            }
        }
    }

    float acc[32];
#pragma unroll
    for (int i = 0; i < 32; ++i) acc[i] = 0.f;

    const int beg = offs[d];
    const int end = beg + cnt[d];
    for (int p = beg; p < end; ++p) {
        int e = sorted[p];
        int src = eidx[e];
        const unsigned short* prow = PQ + (size_t)src * 1024 + c0;
#pragma unroll
        for (int c = 0; c < 4; ++c) {
            bf16x8 pv = *(const bf16x8*)(prow + c * 8);
#pragma unroll
            for (int jp = 0; jp < 4; ++jp) {
                unsigned q = qb[c * 4 + jp];
                float p0 = bflo((unsigned)(unsigned short)pv[jp * 2]);
                float p1 = bflo((unsigned)(unsigned short)pv[jp * 2 + 1]);
                acc[c * 8 + jp * 2]     += fmaxf(p0 + bflo(q), 0.f);
                acc[c * 8 + jp * 2 + 1] += fmaxf(p1 + bfhi(q), 0.f);
            }
        }
    }

    // write hidden-sum to LDS (bf16, swizzled)
#pragma unroll
    for (int c = 0; c < 4; ++c) {
        uint4 v;
        v.x = pack2(acc[c * 8 + 0], acc[c * 8 + 1]);
        v.y = pack2(acc[c * 8 + 2], acc[c * 8 + 3]);
        v.z = pack2(acc[c * 8 + 4], acc[c * 8 + 5]);
        v.w = pack2(acc[c * 8 + 6], acc[c * 8 + 7]);
        int byte = (dsub * 1024 + (c0 + c * 8) * 2) ^ ((dsub & 7) << 4);
        *(uint4*)(smem + byte) = v;
    }
    __syncthreads();

    // GEMM2: 32 rows x 256 cols, K=512. 8 waves, wave w owns cols [32w, 32w+32)
    const int lane = tid & 63;
    const int w = tid >> 6;
    const int lo = lane & 15;
    const int hi = lane >> 4;

    f32x4 acc2[2][2];
#pragma unroll
    for (int i = 0; i < 2; ++i)
#pragma unroll
        for (int j = 0; j < 2; ++j) acc2[i][j] = (f32x4){0.f, 0.f, 0.f, 0.f};

    for (int ks = 0; ks < 512; ks += 32) {
        bf16x8 af[2];
#pragma unroll
        for (int rf = 0; rf < 2; ++rf) {
            int row = rf * 16 + lo;
            int byte = (row * 1024 + (ks + 8 * hi) * 2) ^ ((row & 7) << 4);
            af[rf] = *(const bf16x8*)(smem + byte);
        }
#pragma unroll
        for (int cf = 0; cf < 2; ++cf) {
            int col = w * 32 + cf * 16 + lo;
            bf16x8 bfr = *(const bf16x8*)(w2t + (size_t)col * 512 + ks + 8 * hi);
#pragma unroll
            for (int rf = 0; rf < 2; ++rf)
                acc2[rf][cf] = __builtin_amdgcn_mfma_f32_16x16x32_bf16(af[rf], bfr, acc2[rf][cf], 0, 0, 0);
        }
    }

#pragma unroll
    for (int cf = 0; cf < 2; ++cf) {
        int col = w * 32 + cf * 16 + lo;
        float bb = b2[col];
#pragma unroll
        for (int rf = 0; rf < 2; ++rf) {
#pragma unroll
            for (int r = 0; r < 4; ++r) {
                int row = rf * 16 + hi * 4 + r;
                float degf = (float)cnt[d0 + row];
                float v = acc2[rf][cf][r] + degf * bb;
                aggb[(size_t)(d0 + row) * 256 + col] = f2bf(v);
            }
        }
    }
}

// ---------- update MLP: out = h + mlp([h, agg]) ----------
// 32-row tiles, 256 threads (4 waves)
__global__ __launch_bounds__(256, 4) void upd_kernel(
    const float* __restrict__ h,              // [40000][256] f32
    const unsigned short* __restrict__ aggb,  // [40000][256] bf16
    const unsigned short* __restrict__ u1t,   // [512][512] bf16
    const float* __restrict__ b1,
    const unsigned short* __restrict__ u2t,   // [256][512] bf16
    const float* __restrict__ b2,
    float* __restrict__ outp) {
    __shared__ char smem[32 * 1024];  // [32][512] bf16, swizzled (X, then hidden)
    const int tid = threadIdx.x;
    const int row0 = blockIdx.x * 32;

    // gather X = [h_row f32->bf16 | agg_row bf16]: 32 rows x 64 16B-chunks
#pragma unroll
    for (int it = 0; it < 8; ++it) {
        int linear = it * 256 + tid;
        int row = linear >> 6;
        int c8 = linear & 63;
        int grow = row0 + row;
        uint4 v;
        if (c8 < 32) {
            const float* src = h + (size_t)grow * H_ + c8 * 8;
            float4 a = *(const float4*)src;
            float4 b = *(const float4*)(src + 4);
            v.x = pack2(a.x, a.y);
            v.y = pack2(a.z, a.w);
            v.z = pack2(b.x, b.y);
            v.w = pack2(b.z, b.w);
        } else {
            v = *(const uint4*)(aggb + (size_t)grow * 256 + (c8 - 32) * 8);
        }
        int byte = (row * 1024 + c8 * 16) ^ ((row & 7) << 4);
        *(uint4*)(smem + byte) = v;
    }
    __syncthreads();

    const int lane = tid & 63;
    const int w = tid >> 6;
    const int lo = lane & 15;
    const int hi = lane >> 4;

    // GEMM1: hidden = relu(X @ U1 + b1); wave w cols [128w, 128w+128)
    f32x4 acc[2][8];
#pragma unroll
    for (int i = 0; i < 2; ++i)
#pragma unroll
        for (int j = 0; j < 8; ++j) acc[i][j] = (f32x4){0.f, 0.f, 0.f, 0.f};

    for (int ks = 0; ks < 512; ks += 32) {
        bf16x8 af[2];
#pragma unroll
        for (int rf = 0; rf < 2; ++rf) {
            int row = rf * 16 + lo;
            int byte = (row * 1024 + (ks + 8 * hi) * 2) ^ ((row & 7) << 4);
            af[rf] = *(const bf16x8*)(smem + byte);
        }
#pragma unroll
        for (int cf = 0; cf < 8; ++cf) {
            int col = w * 128 + cf * 16 + lo;
            bf16x8 bfr = *(const bf16x8*)(u1t + (size_t)col * 512 + ks + 8 * hi);
#pragma unroll
            for (int rf = 0; rf < 2; ++rf)
                acc[rf][cf] = __builtin_amdgcn_mfma_f32_16x16x32_bf16(af[rf], bfr, acc[rf][cf], 0, 0, 0);
        }
    }
    __syncthreads();

#pragma unroll
    for (int cf = 0; cf < 8; ++cf) {
        int col = w * 128 + cf * 16 + lo;
        float bb = b1[col];
#pragma unroll
        for (int rf = 0; rf < 2; ++rf) {
#pragma unroll
            for (int r = 0; r < 4; ++r) {
                float v = fmaxf(acc[rf][cf][r] + bb, 0.f);
                int row = rf * 16 + hi * 4 + r;
                int byte = (row * 1024 + col * 2) ^ ((row & 7) << 4);
                *(unsigned short*)(smem + byte) = f2bf(v);
            }
        }
    }
    __syncthreads();

    // GEMM2: y = hidden @ U2 + b2; wave w cols [64w, 64w+64)
    f32x4 acc2[2][4];
#pragma unroll
    for (int i = 0; i < 2; ++i)
#pragma unroll
        for (int j = 0; j < 4; ++j) acc2[i][j] = (f32x4){0.f, 0.f, 0.f, 0.f};

    for (int ks = 0; ks < 512; ks += 32) {
        bf16x8 af[2];
#pragma unroll
        for (int rf = 0; rf < 2; ++rf) {
            int row = rf * 16 + lo;
            int byte = (row * 1024 + (ks + 8 * hi) * 2) ^ ((row & 7) << 4);
            af[rf] = *(const bf16x8*)(smem + byte);
        }
#pragma unroll
        for (int cf = 0; cf < 4; ++cf) {
            int col = w * 64 + cf * 16 + lo;
            bf16x8 bfr = *(const bf16x8*)(u2t + (size_t)col * 512 + ks + 8 * hi);
#pragma unroll
            for (int rf = 0; rf < 2; ++rf)
                acc2[rf][cf] = __builtin_amdgcn_mfma_f32_16x16x32_bf16(af[rf], bfr, acc2[rf][cf], 0, 0, 0);
        }
    }

#pragma unroll
    for (int cf = 0; cf < 4; ++cf) {
        int col = w * 64 + cf * 16 + lo;
        float bb = b2[col];
#pragma unroll
        for (int rf = 0; rf < 2; ++rf) {
#pragma unroll
            for (int r = 0; r < 4; ++r) {
                int row = rf * 16 + hi * 4 + r;
                size_t o = (size_t)(row0 + row) * H_ + col;
                outp[o] = h[o] + acc2[rf][cf][r] + bb;
            }
        }
    }
}

extern "C" void kernel_launch(void* const* d_in, const int* in_sizes, int n_in,
                              void* d_out, int out_size, void* d_ws, size_t ws_size,
                              hipStream_t stream) {
    const float* h      = (const float*)d_in[0];
    const int*   eidx   = (const int*)d_in[1];
    const float* msg_w1 = (const float*)d_in[2];
    const float* msg_b1 = (const float*)d_in[3];
    const float* msg_w2 = (const float*)d_in[4];
    const float* msg_b2 = (const float*)d_in[5];
    const float* upd_w1 = (const float*)d_in[6];
    const float* upd_b1 = (const float*)d_in[7];
    const float* upd_w2 = (const float*)d_in[8];
    const float* upd_b2 = (const float*)d_in[9];
    float* out = (float*)d_out;

    char* ws = (char*)d_ws;
    size_t off = 0;
    auto alloc = [&](size_t bytes) {
        char* p = ws + off;
        off = (off + bytes + 255) & ~(size_t)255;
        return p;
    };
    unsigned short* PQ    = (unsigned short*)alloc((size_t)N_ * 1024 * 2);   // 41 MB (per batch, reused)
    unsigned short* aggb  = (unsigned short*)alloc((size_t)B_ * N_ * 256 * 2); // 20.5 MB
    unsigned short* w1pq  = (unsigned short*)alloc(1024 * 256 * 2);
    unsigned short* w2t   = (unsigned short*)alloc(256 * 512 * 2);
    unsigned short* u1t   = (unsigned short*)alloc(512 * 512 * 2);
    unsigned short* u2t   = (unsigned short*)alloc(256 * 512 * 2);
    int* cnt    = (int*)alloc(N_ * 4);
    int* offs   = (int*)alloc((N_ + 1) * 4);
    int* cursor = (int*)alloc(N_ * 4);
    int* sorted = (int*)alloc(E_ * 4);
    if (ws_size < off) return;

    hipMemsetAsync(cnt, 0, N_ * 4, stream);
    conv_w1pq<<<64, 256, 0, stream>>>(msg_w1, w1pq);
    conv_t<<<64, 256, 0, stream>>>(msg_w2, w2t, 512, 256);
    conv_t<<<128, 256, 0, stream>>>(upd_w1, u1t, 512, 512);
    conv_t<<<64, 256, 0, stream>>>(upd_w2, u2t, 512, 256);

    hist_kernel<<<256, 256, 0, stream>>>(eidx, cnt);
    scan_kernel<<<1, 1024, 0, stream>>>(cnt, offs, cursor);
    scatter_kernel<<<256, 256, 0, stream>>>(eidx, cursor, sorted);

    for (int b = 0; b < B_; ++b) {
        pq_gemm<<<N_ / 32, 512, 0, stream>>>(h + (size_t)b * N_ * H_, w1pq, PQ);
        agg_kernel<<<N_ / 32, 512, 0, stream>>>(PQ, eidx, sorted, offs, cnt, w2t,
                                                msg_b1, msg_b2,
                                                aggb + (size_t)b * N_ * 256);
    }

    upd_kernel<<<(B_ * N_) / 32, 256, 0, stream>>>(h, aggb, u1t, upd_b1, u2t, upd_b2, out);
}